// Round 1
// baseline (239.412 us; speedup 1.0000x reference)
//
#include <hip/hip_runtime.h>
#include <hip/hip_bf16.h>

#define B_ 16
#define L_ 1024
#define DM 256
#define DI 512
#define NS 16
#define E48 48
#define GCH 16
#define LC 64

// ws layout (float offsets)
#define O_XPRE 0ULL                 // (B,L,DI) pre-conv x   33.5MB
#define O_XS   (8388608ULL)         // (B,L,DI) conv+silu x  33.5MB
#define O_DT   O_XPRE               // dt overlays x_pre (x_pre dead after conv)
#define O_XDBL (16777216ULL)        // (B,L,48)
#define O_WINT (17563648ULL)        // w_in top-half transposed (256x512)
#define O_WXT  (17694720ULL)        // w_x transposed (512x48)
#define O_LG   (17719296ULL)        // (B,G,DI,16) chunk partial states
#define O_TSUM (19816448ULL)        // (B,G,DI) chunk dt sums
#define O_ZS   (19947520ULL)        // (B,DI) silu(z_last)
#define O_YF   (19955712ULL)        // (B,DI) final y
// total = 19963904 floats = 79.9 MB

__device__ __forceinline__ float siluf(float v) { return v / (1.f + __expf(-v)); }
__device__ __forceinline__ float softplusf(float v) { return (v > 20.f) ? v : log1pf(__expf(v)); }

// ---- prep: transpose w_in (top half) and w_x for coalesced GEMM loads ----
__global__ void k_prep(const float* __restrict__ w_in, const float* __restrict__ w_x,
                       float* __restrict__ ws) {
    int i = blockIdx.x * 256 + threadIdx.x;
    if (i < 131072) { int k = i >> 9, e = i & 511; ws[O_WINT + i] = w_in[(size_t)e * DM + k]; }
    if (i < 24576)  { int k = i / 48, e = i % 48;  ws[O_WXT + i] = w_x[(size_t)e * DI + k]; }
}

// ---- z at last position only: zs[b,d] = silu(u[b,lb] . w_in[512+d,:]) ----
__global__ void k_zlast(const int* __restrict__ rna, const int* __restrict__ tid_,
                        const int* __restrict__ slen, const float* __restrict__ tis_emb,
                        const float* __restrict__ seq_emb, const float* __restrict__ w_in,
                        float* __restrict__ ws) {
    int b = blockIdx.x, t = threadIdx.x;
    __shared__ float su[DM];
    int lb = slen[b] - 1;
    if (t < 192) { int tok = rna[b * L_ + lb]; su[t] = seq_emb[(size_t)tok * 192 + t]; }
    else         { su[t] = tis_emb[(size_t)tid_[b] * 64 + (t - 192)]; }
    __syncthreads();
    for (int d = t; d < DI; d += 256) {
        const float* wr = w_in + (size_t)(DI + d) * DM;
        float acc = 0.f;
        for (int k = 0; k < DM; k++) acc += su[k] * wr[k];
        ws[O_ZS + (size_t)b * DI + d] = siluf(acc);
    }
}

// ---- GEMM1 (fused embedding): x_pre[b,l,e] = u[b,l,:] . w_in[e,:], e<512 ----
__global__ __launch_bounds__(256) void k_gemm1(const int* __restrict__ rna,
        const int* __restrict__ tid_, const int* __restrict__ slen,
        const float* __restrict__ tis_emb, const float* __restrict__ seq_emb,
        float* __restrict__ ws) {
    int n0 = blockIdx.x * 64;
    int rb = blockIdx.y;
    int b = rb >> 4, l0 = (rb & 15) * 64;
    int lb = slen[b] - 1;
    if (l0 > lb) return;
    const float* winT = ws + O_WINT;
    __shared__ float As[16][64];
    __shared__ float Bs[16][64];
    __shared__ int   stok[64];
    __shared__ float stis[64];
    int t = threadIdx.x;
    if (t < 64) stok[t] = rna[b * L_ + l0 + t];
    else if (t < 128) stis[t - 64] = tis_emb[(size_t)tid_[b] * 64 + (t - 64)];
    __syncthreads();
    float acc[4][4] = {};
    int tx = t & 15, ty = t >> 4;
    int lr = t & 63, kg = t >> 6;       // A-load mapping
    int lc4 = (t & 15) * 4, lkk = t >> 4; // B-load mapping
    for (int k0 = 0; k0 < DM; k0 += 16) {
        int kbase = k0 + kg * 4;
        if (kbase < 192) {
            float4 v = *(const float4*)(seq_emb + (size_t)stok[lr] * 192 + kbase);
            As[kg * 4 + 0][lr] = v.x; As[kg * 4 + 1][lr] = v.y;
            As[kg * 4 + 2][lr] = v.z; As[kg * 4 + 3][lr] = v.w;
        } else {
            As[kg * 4 + 0][lr] = stis[kbase - 192 + 0];
            As[kg * 4 + 1][lr] = stis[kbase - 192 + 1];
            As[kg * 4 + 2][lr] = stis[kbase - 192 + 2];
            As[kg * 4 + 3][lr] = stis[kbase - 192 + 3];
        }
        float4 w = *(const float4*)(winT + (size_t)(k0 + lkk) * DI + n0 + lc4);
        Bs[lkk][lc4 + 0] = w.x; Bs[lkk][lc4 + 1] = w.y;
        Bs[lkk][lc4 + 2] = w.z; Bs[lkk][lc4 + 3] = w.w;
        __syncthreads();
#pragma unroll
        for (int kk = 0; kk < 16; kk++) {
            float4 a = *(const float4*)&As[kk][ty * 4];
            float4 bb = *(const float4*)&Bs[kk][tx * 4];
            acc[0][0] += a.x * bb.x; acc[0][1] += a.x * bb.y; acc[0][2] += a.x * bb.z; acc[0][3] += a.x * bb.w;
            acc[1][0] += a.y * bb.x; acc[1][1] += a.y * bb.y; acc[1][2] += a.y * bb.z; acc[1][3] += a.y * bb.w;
            acc[2][0] += a.z * bb.x; acc[2][1] += a.z * bb.y; acc[2][2] += a.z * bb.z; acc[2][3] += a.z * bb.w;
            acc[3][0] += a.w * bb.x; acc[3][1] += a.w * bb.y; acc[3][2] += a.w * bb.z; acc[3][3] += a.w * bb.w;
        }
        __syncthreads();
    }
#pragma unroll
    for (int i = 0; i < 4; i++) {
        float4 v = make_float4(acc[i][0], acc[i][1], acc[i][2], acc[i][3]);
        *(float4*)(ws + O_XPRE + (size_t)(b * L_ + l0 + ty * 4 + i) * DI + n0 + tx * 4) = v;
    }
}

// ---- causal depthwise conv (k=4) + bias + silu ----
__global__ void k_conv(const int* __restrict__ slen, const float* __restrict__ conv_w,
                       const float* __restrict__ conv_b, float* __restrict__ ws) {
    int b = blockIdx.y, l0 = blockIdx.x * 64;
    int lb = slen[b] - 1;
    if (l0 > lb) return;
    int lmax = min(l0 + 63, lb);
    const float* xp = ws + O_XPRE;
    float* xs = ws + O_XS;
    for (int dd = 0; dd < 2; dd++) {
        int d = threadIdx.x + dd * 256;
        float w0 = conv_w[d * 4 + 0], w1 = conv_w[d * 4 + 1];
        float w2 = conv_w[d * 4 + 2], w3 = conv_w[d * 4 + 3];
        float bias = conv_b[d];
        size_t base = (size_t)b * L_ * DI + d;
        float xm3 = (l0 - 3 >= 0) ? xp[base + (size_t)(l0 - 3) * DI] : 0.f;
        float xm2 = (l0 - 2 >= 0) ? xp[base + (size_t)(l0 - 2) * DI] : 0.f;
        float xm1 = (l0 - 1 >= 0) ? xp[base + (size_t)(l0 - 1) * DI] : 0.f;
        for (int l = l0; l <= lmax; l++) {
            float cur = xp[base + (size_t)l * DI];
            float v = fmaf(w0, xm3, fmaf(w1, xm2, fmaf(w2, xm1, fmaf(w3, cur, bias))));
            xs[base + (size_t)l * DI] = siluf(v);
            xm3 = xm2; xm2 = xm1; xm1 = cur;
        }
    }
}

// ---- x_dbl (48 outs) + dt = softplus(dt_raw @ w_dt^T + b_dt) ----
__global__ __launch_bounds__(256) void k_xdbl_dt(const int* __restrict__ slen,
        const float* __restrict__ w_dt, const float* __restrict__ b_dt,
        float* __restrict__ ws) {
    int b = blockIdx.y, l0 = blockIdx.x * 4;
    int lb = slen[b] - 1;
    if (l0 > lb) return;
    const float* xs = ws + O_XS;
    const float* wxT = ws + O_WXT;
    float* xdbl = ws + O_XDBL;
    float* dt = ws + O_DT;
    __shared__ float xr[4][DI];
    __shared__ float xd[4][E48];
    int t = threadIdx.x;
    for (int r = 0; r < 4; r++) {
        int l = l0 + r;
        float2 v = (l <= lb) ? *(const float2*)(xs + (size_t)(b * L_ + l) * DI + t * 2)
                             : make_float2(0.f, 0.f);
        xr[r][t * 2] = v.x; xr[r][t * 2 + 1] = v.y;
    }
    __syncthreads();
    if (t < 192) {
        int r = t / 48, e = t % 48;
        float acc = 0.f;
        for (int k = 0; k < DI; k++) acc += xr[r][k] * wxT[k * 48 + e];
        xd[r][e] = acc;
        if (l0 + r <= lb) xdbl[(size_t)(b * L_ + l0 + r) * E48 + e] = acc;
    }
    __syncthreads();
    for (int r = 0; r < 4; r++) {
        if (l0 + r > lb) break;
        for (int dd = 0; dd < 2; dd++) {
            int d = t + dd * 256;
            float acc = b_dt[d];
            const float* wr = w_dt + (size_t)d * 16;
#pragma unroll
            for (int j = 0; j < 16; j++) acc += xd[r][j] * wr[j];
            dt[(size_t)(b * L_ + l0 + r) * DI + d] = softplusf(acc);
        }
    }
}

// ---- scan phase A: per (b, chunk) local recurrence from h=0 ----
__global__ __launch_bounds__(512) void k_scanA(const int* __restrict__ slen,
        const float* __restrict__ A_log, float* __restrict__ ws) {
    int b = blockIdx.y, g = blockIdx.x;
    int lb = slen[b] - 1;
    if (g * LC > lb) return;
    int d = threadIdx.x;
    const float* dt = ws + O_DT;
    const float* xs = ws + O_XS;
    const float* xdbl = ws + O_XDBL;
    float An[16];
#pragma unroll
    for (int n = 0; n < 16; n++) An[n] = -__expf(A_log[(size_t)d * 16 + n]);
    float h[16];
#pragma unroll
    for (int n = 0; n < 16; n++) h[n] = 0.f;
    float sdt = 0.f;
    int imax = min(LC - 1, lb - g * LC);
    for (int i = 0; i <= imax; i++) {
        size_t rbase = (size_t)(b * L_ + g * LC + i);
        float dtv = dt[rbase * DI + d];
        float xv = xs[rbase * DI + d];
        const float4* bp = (const float4*)(xdbl + rbase * E48 + 16);
        float4 b0 = bp[0], b1 = bp[1], b2 = bp[2], b3 = bp[3];
        float Bv[16] = {b0.x, b0.y, b0.z, b0.w, b1.x, b1.y, b1.z, b1.w,
                        b2.x, b2.y, b2.z, b2.w, b3.x, b3.y, b3.z, b3.w};
        float w = dtv * xv;
        sdt += dtv;
#pragma unroll
        for (int n = 0; n < 16; n++) h[n] = fmaf(__expf(dtv * An[n]), h[n], w * Bv[n]);
    }
    float* Lg = ws + O_LG + ((size_t)(b * GCH + g) * DI + d) * 16;
#pragma unroll
    for (int n = 0; n < 16; n++) Lg[n] = h[n];
    ws[O_TSUM + (size_t)(b * GCH + g) * DI + d] = sdt;
}

// ---- scan phase B: combine chunks, produce y at lb, apply D-skip and silu(z) ----
__global__ void k_scanB(const int* __restrict__ slen, const float* __restrict__ A_log,
                        const float* __restrict__ Dp, float* __restrict__ ws) {
    int b = blockIdx.y;
    int d = blockIdx.x * 256 + threadIdx.x;
    int lb = slen[b] - 1, gb = lb >> 6;
    float An[16];
#pragma unroll
    for (int n = 0; n < 16; n++) An[n] = -__expf(A_log[(size_t)d * 16 + n]);
    float h[16];
#pragma unroll
    for (int n = 0; n < 16; n++) h[n] = 0.f;
    float R = 0.f;
    for (int g = gb; g >= 0; g--) {
        const float4* Lg = (const float4*)(ws + O_LG + ((size_t)(b * GCH + g) * DI + d) * 16);
        float4 v0 = Lg[0], v1 = Lg[1], v2 = Lg[2], v3 = Lg[3];
        float lv[16] = {v0.x, v0.y, v0.z, v0.w, v1.x, v1.y, v1.z, v1.w,
                        v2.x, v2.y, v2.z, v2.w, v3.x, v3.y, v3.z, v3.w};
        float T = ws[O_TSUM + (size_t)(b * GCH + g) * DI + d];
#pragma unroll
        for (int n = 0; n < 16; n++) h[n] = fmaf(__expf(An[n] * R), lv[n], h[n]);
        R += T;
    }
    const float* C = ws + O_XDBL + (size_t)(b * L_ + lb) * E48 + 32;
    float y = 0.f;
#pragma unroll
    for (int n = 0; n < 16; n++) y += h[n] * C[n];
    float xv = ws[O_XS + (size_t)(b * L_ + lb) * DI + d];
    y = (y + xv * Dp[d]) * ws[O_ZS + (size_t)b * DI + d];
    ws[O_YF + (size_t)b * DI + d] = y;
}

// ---- head: out_proj -> relu MLP -> scalar ----
__global__ __launch_bounds__(256) void k_head(const float* __restrict__ w_out,
        const float* __restrict__ w1, const float* __restrict__ b1,
        const float* __restrict__ w2, const float* __restrict__ b2,
        const float* __restrict__ ws, float* __restrict__ out) {
    int b = blockIdx.x, t = threadIdx.x;
    __shared__ float sy[DI];
    __shared__ float sol[DM];
    __shared__ float red[256];
    *(float2*)&sy[t * 2] = *(const float2*)(ws + O_YF + (size_t)b * DI + t * 2);
    __syncthreads();
    {
        float acc = 0.f;
        const float* wr = w_out + (size_t)t * DI;
        for (int k = 0; k < DI; k++) acc += sy[k] * wr[k];
        sol[t] = acc;
    }
    __syncthreads();
    float part = 0.f;
    for (int dd = 0; dd < 2; dd++) {
        int j = t + dd * 256;
        float acc = b1[j];
        const float* wr = w1 + (size_t)j * DM;
        for (int k = 0; k < DM; k++) acc += sol[k] * wr[k];
        part += fmaxf(acc, 0.f) * w2[j];
    }
    red[t] = part;
    __syncthreads();
    for (int s = 128; s > 0; s >>= 1) { if (t < s) red[t] += red[t + s]; __syncthreads(); }
    if (t == 0) out[b] = red[0] + b2[0];
}

extern "C" void kernel_launch(void* const* d_in, const int* in_sizes, int n_in,
                              void* d_out, int out_size, void* d_ws, size_t ws_size,
                              hipStream_t stream) {
    const int* rna = (const int*)d_in[0];
    const int* tid_ = (const int*)d_in[1];
    const int* slen = (const int*)d_in[2];
    const float* tis_emb = (const float*)d_in[3];
    const float* seq_emb = (const float*)d_in[4];
    const float* w_in = (const float*)d_in[5];
    const float* conv_w = (const float*)d_in[6];
    const float* conv_b = (const float*)d_in[7];
    // w_x = d_in[8] (transposed in k_prep)
    const float* w_x = (const float*)d_in[8];
    const float* w_dt = (const float*)d_in[9];
    const float* b_dt = (const float*)d_in[10];
    const float* A_log = (const float*)d_in[11];
    const float* Dp = (const float*)d_in[12];
    const float* w_out = (const float*)d_in[13];
    const float* w1 = (const float*)d_in[14];
    const float* b1 = (const float*)d_in[15];
    const float* w2 = (const float*)d_in[16];
    const float* b2 = (const float*)d_in[17];
    float* ws = (float*)d_ws;
    float* out = (float*)d_out;

    hipLaunchKernelGGL(k_prep, dim3(512), dim3(256), 0, stream, w_in, w_x, ws);
    hipLaunchKernelGGL(k_zlast, dim3(16), dim3(256), 0, stream,
                       rna, tid_, slen, tis_emb, seq_emb, w_in, ws);
    hipLaunchKernelGGL(k_gemm1, dim3(8, 256), dim3(256), 0, stream,
                       rna, tid_, slen, tis_emb, seq_emb, ws);
    hipLaunchKernelGGL(k_conv, dim3(16, 16), dim3(256), 0, stream, slen, conv_w, conv_b, ws);
    hipLaunchKernelGGL(k_xdbl_dt, dim3(256, 16), dim3(256), 0, stream, slen, w_dt, b_dt, ws);
    hipLaunchKernelGGL(k_scanA, dim3(16, 16), dim3(512), 0, stream, slen, A_log, ws);
    hipLaunchKernelGGL(k_scanB, dim3(2, 16), dim3(256), 0, stream, slen, A_log, Dp, ws);
    hipLaunchKernelGGL(k_head, dim3(16), dim3(256), 0, stream, w_out, w1, b1, w2, b2, ws, out);
}